// Round 1
// baseline (50.455 us; speedup 1.0000x reference)
//
#include <hip/hip_runtime.h>

// HierarchicalSoftmax: B=65536 rows, N=520 cols fp32.
// Layout per row: cols 0..7 = "heads" segment (softmax over 8),
// cols 8+g*64 .. 8+g*64+63 = children segment g (softmax over 64), g=0..7.
//
// One wave (64 lanes) per row. Children: 2 iterations of float4 loads;
// each 16-lane subgroup owns one 64-float segment (16 lanes x float4).
// Reduction via __shfl_xor within width-16 groups. Head: lanes 0..7,
// width-8 shuffles. All global accesses are 16B-aligned and coalesced.

#define HS_B 65536
#define HS_N 520

__global__ void HierarchicalSoftmax_88914412962167_kernel(
    const float* __restrict__ x, float* __restrict__ out) {
    const int gtid   = blockIdx.x * blockDim.x + threadIdx.x;
    const int wave   = gtid >> 6;
    const int lane   = threadIdx.x & 63;
    const int nwaves = (gridDim.x * blockDim.x) >> 6;

    for (int row = wave; row < HS_B; row += nwaves) {
        const float* xr = x   + (size_t)row * HS_N;
        float*     orow = out + (size_t)row * HS_N;

        // ---- children: 8 segments of 64 floats, 16 lanes per segment ----
#pragma unroll
        for (int j = 0; j < 2; ++j) {
            const float4 v = *reinterpret_cast<const float4*>(xr + 8 + j * 256 + lane * 4);
            float m = fmaxf(fmaxf(v.x, v.y), fmaxf(v.z, v.w));
#pragma unroll
            for (int mask = 8; mask >= 1; mask >>= 1)
                m = fmaxf(m, __shfl_xor(m, mask, 16));
            float4 e;
            e.x = __expf(v.x - m);
            e.y = __expf(v.y - m);
            e.z = __expf(v.z - m);
            e.w = __expf(v.w - m);
            float s = (e.x + e.y) + (e.z + e.w);
#pragma unroll
            for (int mask = 8; mask >= 1; mask >>= 1)
                s += __shfl_xor(s, mask, 16);
            const float inv = 1.0f / s;
            float4 o;
            o.x = e.x * inv;
            o.y = e.y * inv;
            o.z = e.z * inv;
            o.w = e.w * inv;
            *reinterpret_cast<float4*>(orow + 8 + j * 256 + lane * 4) = o;
        }

        // ---- heads: 8 floats, lanes 0..7, width-8 butterfly ----
        if (lane < 8) {
            const float h = xr[lane];
            float m = h;
#pragma unroll
            for (int mask = 4; mask >= 1; mask >>= 1)
                m = fmaxf(m, __shfl_xor(m, mask, 8));
            const float e = __expf(h - m);
            float s = e;
#pragma unroll
            for (int mask = 4; mask >= 1; mask >>= 1)
                s += __shfl_xor(s, mask, 8);
            orow[lane] = e / s;
        }
    }
}

extern "C" void kernel_launch(void* const* d_in, const int* in_sizes, int n_in,
                              void* d_out, int out_size, void* d_ws, size_t ws_size,
                              hipStream_t stream) {
    const float* x = (const float*)d_in[0];
    // d_in[1] is the segment map; structure is compile-time known, unused.
    float* out = (float*)d_out;

    const int block = 256;
    const int grid  = 2048;  // 8 blocks/CU * 256 CUs; grid-stride over rows
    HierarchicalSoftmax_88914412962167_kernel<<<grid, block, 0, stream>>>(x, out);
}